// Round 1
// baseline (820.641 us; speedup 1.0000x reference)
//
#include <hip/hip_runtime.h>

#define NTOK 160
#define EDIM 256
#define HH 4
#define DDIM 64
#define NNR 25600          // NTOK*NTOK rows
#define PC 784             // packed projection cols
#define SCALEF 0.125f
#define LNEPS 1e-5f

// ---- workspace layout (float offsets) ----
#define OFF_ELN 0LL
#define OFF_Y   (OFF_ELN + (long long)NNR * EDIM)     //  6,553,600
#define OFF_WP  (OFF_Y   + (long long)NNR * PC)       // 26,624,000
#define OFF_BP  (OFF_WP  + (long long)EDIM * PC)      // 26,824,704
#define OFF_BIN (OFF_BP  + 1024LL)                    // 26,825,728
#define OFF_GIN (OFF_BIN + (long long)NNR * HH)
#define OFF_BOT (OFF_GIN + (long long)NNR * HH)
#define OFF_GOT (OFF_BOT + (long long)NNR * HH)
#define OFF_VA  (OFF_GOT + (long long)NNR * HH)       // 27,235,328
// end = OFF_VA + NNR*512 = 40,342,528 floats (~154 MiB)

__device__ __forceinline__ float wave_sum(float v) {
  #pragma unroll
  for (int o = 1; o < 64; o <<= 1) v += __shfl_xor(v, o, 64);
  return v;
}
__device__ __forceinline__ float wave_max(float v) {
  #pragma unroll
  for (int o = 1; o < 64; o <<= 1) v = fmaxf(v, __shfl_xor(v, o, 64));
  return v;
}

// ---------------- pack weights: Wpack[256][784], bpack[784] ----------------
// col map: [0,256) Q_in (c=h*64+d <- Wq col d*4+h, *SCALE) | [256,320) K_in |
// [320,384) V_in | [384,388) E_in | [388,392) G_in | [392,648) Q_out |
// [648,712) K_out | [712,776) V_out | [776,780) E_out | [780,784) G_out
__global__ void pack_kernel(const float* __restrict__ Wq_in,  const float* __restrict__ bq_in,
                            const float* __restrict__ Wkv_in, const float* __restrict__ bkv_in,
                            const float* __restrict__ Weg_in, const float* __restrict__ beg_in,
                            const float* __restrict__ Wq_out, const float* __restrict__ bq_out,
                            const float* __restrict__ Wkv_out,const float* __restrict__ bkv_out,
                            const float* __restrict__ Weg_out,const float* __restrict__ beg_out,
                            float* __restrict__ Wp, float* __restrict__ bp) {
  int idx = blockIdx.x * blockDim.x + threadIdx.x;
  if (idx >= (EDIM + 1) * PC) return;
  int k = idx / PC, c = idx % PC;
  const float *W, *bias; int col, ncols; float scale = 1.f;
  if (c < 256)      { int h = c >> 6, d = c & 63; W = Wq_in;  bias = bq_in;  col = d*4+h; ncols = 256; scale = SCALEF; }
  else if (c < 320) { W = Wkv_in;  bias = bkv_in;  col = c - 256;        ncols = 128; }
  else if (c < 384) { W = Wkv_in;  bias = bkv_in;  col = 64 + (c - 320); ncols = 128; }
  else if (c < 388) { W = Weg_in;  bias = beg_in;  col = c - 384;        ncols = 8; }
  else if (c < 392) { W = Weg_in;  bias = beg_in;  col = 4 + (c - 388);  ncols = 8; }
  else if (c < 648) { int c2 = c - 392; int h = c2 >> 6, d = c2 & 63;
                      W = Wq_out;  bias = bq_out;  col = d*4+h; ncols = 256; scale = SCALEF; }
  else if (c < 712) { W = Wkv_out; bias = bkv_out; col = c - 648;        ncols = 128; }
  else if (c < 776) { W = Wkv_out; bias = bkv_out; col = 64 + (c - 712); ncols = 128; }
  else if (c < 780) { W = Weg_out; bias = beg_out; col = c - 776;        ncols = 8; }
  else              { W = Weg_out; bias = beg_out; col = 4 + (c - 780);  ncols = 8; }
  if (k < EDIM) Wp[(long long)k * PC + c] = W[(long long)k * ncols + col] * scale;
  else          bp[c] = bias[col] * scale;
}

// ---------------- layernorm: one wave per row ----------------
__global__ __launch_bounds__(256) void ln_kernel(const float* __restrict__ e,
                                                 const float* __restrict__ g,
                                                 const float* __restrict__ b,
                                                 float* __restrict__ eln) {
  int row  = blockIdx.x * 4 + (threadIdx.x >> 6);
  int lane = threadIdx.x & 63;
  float4 x = ((const float4*)(e + (long long)row * EDIM))[lane];
  float s = wave_sum(x.x + x.y + x.z + x.w);
  float mu = s * (1.f / EDIM);
  float d0 = x.x - mu, d1 = x.y - mu, d2 = x.z - mu, d3 = x.w - mu;
  float v = wave_sum(d0*d0 + d1*d1 + d2*d2 + d3*d3);
  float rs = rsqrtf(v * (1.f / EDIM) + LNEPS);
  float4 gg = ((const float4*)g)[lane], bb = ((const float4*)b)[lane];
  float4 y;
  y.x = d0 * rs * gg.x + bb.x;  y.y = d1 * rs * gg.y + bb.y;
  y.z = d2 * rs * gg.z + bb.z;  y.w = d3 * rs * gg.w + bb.w;
  ((float4*)(eln + (long long)row * EDIM))[lane] = y;
}

// ---------------- projection GEMM: Y[25600][784] = eln @ Wp + bp ----------------
__global__ __launch_bounds__(256) void proj_kernel(const float* __restrict__ A,
                                                   const float* __restrict__ Wp,
                                                   const float* __restrict__ bp,
                                                   float* __restrict__ Y) {
  __shared__ float As[32][68];    // [k][m]
  __shared__ float Bs[32][132];   // [k][n]
  const int n0 = blockIdx.x * 128;
  const int m0 = blockIdx.y * 64;
  const int t  = threadIdx.x;
  const int tx = t & 15, ty = t >> 4;
  float acc[4][8];
  #pragma unroll
  for (int a = 0; a < 4; ++a)
    #pragma unroll
    for (int c = 0; c < 8; ++c) acc[a][c] = 0.f;
  for (int k0 = 0; k0 < EDIM; k0 += 32) {
    #pragma unroll
    for (int p = 0; p < 2; ++p) {
      int f = t + p * 256;
      int r = f >> 3, kq = (f & 7) << 2;
      float4 a4 = *(const float4*)&A[(long long)(m0 + r) * EDIM + k0 + kq];
      As[kq + 0][r] = a4.x; As[kq + 1][r] = a4.y;
      As[kq + 2][r] = a4.z; As[kq + 3][r] = a4.w;
    }
    #pragma unroll
    for (int p = 0; p < 4; ++p) {
      int f = t + p * 256;
      int kr = f >> 5, cq = (f & 31) << 2;
      float4 b4 = make_float4(0.f, 0.f, 0.f, 0.f);
      if (n0 + cq + 4 <= PC)
        b4 = *(const float4*)&Wp[(long long)(k0 + kr) * PC + n0 + cq];
      *(float4*)&Bs[kr][cq] = b4;
    }
    __syncthreads();
    #pragma unroll
    for (int kk = 0; kk < 32; ++kk) {
      float4 a4 = *(float4*)&As[kk][ty << 2];
      float4 b0 = *(float4*)&Bs[kk][tx << 3];
      float4 b1 = *(float4*)&Bs[kk][(tx << 3) + 4];
      float av[4] = {a4.x, a4.y, a4.z, a4.w};
      float bv[8] = {b0.x, b0.y, b0.z, b0.w, b1.x, b1.y, b1.z, b1.w};
      #pragma unroll
      for (int a = 0; a < 4; ++a)
        #pragma unroll
        for (int c = 0; c < 8; ++c) acc[a][c] += av[a] * bv[c];
    }
    __syncthreads();
  }
  #pragma unroll
  for (int a = 0; a < 4; ++a) {
    long long row = m0 + (ty << 2) + a;
    #pragma unroll
    for (int c = 0; c < 8; ++c) {
      int col = n0 + (tx << 3) + c;
      if (col < PC) Y[row * PC + col] = acc[a][c] + bp[col];
    }
  }
}

// ---------------- E/G precompute (sigmoid once; out-branch stored transposed) ----------------
__global__ void eg_kernel(const float* __restrict__ Y, const float* __restrict__ mask,
                          float* __restrict__ bin, float* __restrict__ gin,
                          float* __restrict__ boT, float* __restrict__ goT) {
  int idx = blockIdx.x * blockDim.x + threadIdx.x;
  if (idx >= NNR * HH) return;
  int r = idx >> 2, h = idx & 3;
  float m = mask[r];
  const float* yr = Y + (long long)r * PC;
  bin[idx] = yr[384 + h] + m;
  gin[idx] = 1.f / (1.f + __expf(-(yr[388 + h] + m)));
  // r = (k, i) in "out" indexing; store at (i, k)
  int i = r % NTOK, k = r / NTOK;
  int rt = i * NTOK + k;
  boT[rt * 4 + h] = yr[776 + h] + m;
  goT[rt * 4 + h] = 1.f / (1.f + __expf(-(yr[780 + h] + m)));
}

// ---------------- fused attention: grid (i-tile 0..3, j 0..159, branch 0..1) ----------------
__global__ __launch_bounds__(256) void attn_kernel(const float* __restrict__ Y,
                                                   const float* __restrict__ bin,
                                                   const float* __restrict__ gin,
                                                   const float* __restrict__ boT,
                                                   const float* __restrict__ goT,
                                                   float* __restrict__ Va) {
  __shared__ float Kl[160][68];
  __shared__ float Vl[160][68];
  __shared__ float Ql[40][68];
  __shared__ float Sl[160][41];
  const int i0 = blockIdx.x * 40;
  const int j  = blockIdx.y;
  const int br = blockIdx.z;           // 0: in, 1: out
  const int t  = threadIdx.x;
  const int kvbase = br ? 648 : 256;   // K col base; V is +64
  const int qbase  = br ? 392 : 0;
  const float* bias = br ? boT : bin;
  const float* gate = br ? goT : gin;

  // load K/V for this (j, branch): 160 rows x 64
  for (int f = t; f < 160 * 16; f += 256) {
    int k = f >> 4, q = (f & 15) << 2;
    long long ro = br ? ((long long)(k * NTOK + j) * PC) : ((long long)(j * NTOK + k) * PC);
    *(float4*)&Kl[k][q] = *(const float4*)&Y[ro + kvbase + q];
    *(float4*)&Vl[k][q] = *(const float4*)&Y[ro + kvbase + 64 + q];
  }
  const int tx = t & 31, ty = t >> 5;  // compute-phase layout (32,8)
  const int lane = t & 63, w = t >> 6;

  for (int h = 0; h < HH; ++h) {
    __syncthreads();  // prev-iter PV done with Sl; K/V ready on first iter after next sync
    for (int f = t; f < 40 * 16; f += 256) {
      int ii = f >> 4, q = (f & 15) << 2;
      *(float4*)&Ql[ii][q] = *(const float4*)&Y[(long long)((i0 + ii) * NTOK + j) * PC + qbase + h * 64 + q];
    }
    __syncthreads();
    // ---- S = Q K^T  (thread: k-tile 5 @ tx*5, i-tile 5 @ ty*5) ----
    {
      const int k0 = tx * 5, iq = ty * 5;
      float s[5][5];
      #pragma unroll
      for (int a = 0; a < 5; ++a)
        #pragma unroll
        for (int c = 0; c < 5; ++c) s[a][c] = 0.f;
      #pragma unroll 4
      for (int dq = 0; dq < 16; ++dq) {
        float4 qv[5], kv[5];
        #pragma unroll
        for (int a = 0; a < 5; ++a) qv[a] = *(const float4*)&Ql[iq + a][dq << 2];
        #pragma unroll
        for (int c = 0; c < 5; ++c) kv[c] = *(const float4*)&Kl[k0 + c][dq << 2];
        #pragma unroll
        for (int a = 0; a < 5; ++a)
          #pragma unroll
          for (int c = 0; c < 5; ++c)
            s[a][c] += qv[a].x * kv[c].x + qv[a].y * kv[c].y + qv[a].z * kv[c].z + qv[a].w * kv[c].w;
      }
      #pragma unroll
      for (int a = 0; a < 5; ++a)
        #pragma unroll
        for (int c = 0; c < 5; ++c) Sl[k0 + c][iq + a] = s[a][c];
    }
    __syncthreads();
    // ---- softmax over k per row (wave w handles rows w, w+4, ...) ----
    for (int ii = w; ii < 40; ii += 4) {
      int rb = (i0 + ii) * NTOK;
      int k1 = lane, k2 = lane + 64, k3 = lane + 128;
      float l0 = Sl[k1][ii] + bias[(rb + k1) * 4 + h];
      float l1 = Sl[k2][ii] + bias[(rb + k2) * 4 + h];
      float l2 = (k3 < 160) ? Sl[k3][ii] + bias[(rb + k3) * 4 + h] : -1e30f;
      float m = wave_max(fmaxf(fmaxf(l0, l1), l2));
      float p0 = __expf(l0 - m), p1 = __expf(l1 - m);
      float p2 = (k3 < 160) ? __expf(l2 - m) : 0.f;
      float inv = 1.f / wave_sum(p0 + p1 + p2);
      Sl[k1][ii] = p0 * inv * gate[(rb + k1) * 4 + h];
      Sl[k2][ii] = p1 * inv * gate[(rb + k2) * 4 + h];
      if (k3 < 160) Sl[k3][ii] = p2 * inv * gate[(rb + k3) * 4 + h];
    }
    __syncthreads();
    // ---- PV: thread i-tile 5 @ ty*5, d-tile 2 @ tx*2 ----
    {
      const int iq = ty * 5, d0 = tx * 2;
      float va[5][2];
      #pragma unroll
      for (int a = 0; a < 5; ++a) { va[a][0] = 0.f; va[a][1] = 0.f; }
      for (int k = 0; k < 160; ++k) {
        float2 v2 = *(const float2*)&Vl[k][d0];
        #pragma unroll
        for (int a = 0; a < 5; ++a) {
          float av = Sl[k][iq + a];
          va[a][0] += av * v2.x;
          va[a][1] += av * v2.y;
        }
      }
      #pragma unroll
      for (int a = 0; a < 5; ++a) {
        long long o = (long long)((i0 + iq + a) * NTOK + j) * 512 + br * 256 + h * 64 + d0;
        *(float2*)&Va[o] = make_float2(va[a][0], va[a][1]);
      }
    }
  }
}

// ---------------- output GEMM: out = Va2 @ Wo(perm rows) + bo ----------------
__global__ __launch_bounds__(256) void out_kernel(const float* __restrict__ Va,
                                                  const float* __restrict__ Wo,
                                                  const float* __restrict__ bo,
                                                  float* __restrict__ out) {
  __shared__ float As[32][68];
  __shared__ float Bs[32][132];
  const int n0 = blockIdx.x * 128;
  const int m0 = blockIdx.y * 64;
  const int t  = threadIdx.x;
  const int tx = t & 15, ty = t >> 4;
  float acc[4][8];
  #pragma unroll
  for (int a = 0; a < 4; ++a)
    #pragma unroll
    for (int c = 0; c < 8; ++c) acc[a][c] = 0.f;
  for (int k0 = 0; k0 < 512; k0 += 32) {
    #pragma unroll
    for (int p = 0; p < 2; ++p) {
      int f = t + p * 256;
      int r = f >> 3, kq = (f & 7) << 2;
      float4 a4 = *(const float4*)&Va[(long long)(m0 + r) * 512 + k0 + kq];
      As[kq + 0][r] = a4.x; As[kq + 1][r] = a4.y;
      As[kq + 2][r] = a4.z; As[kq + 3][r] = a4.w;
    }
    #pragma unroll
    for (int p = 0; p < 4; ++p) {
      int f = t + p * 256;
      int kr = f >> 5, cq = (f & 31) << 2;
      int kk = k0 + kr;
      // Va col kk = br*256 + h*64 + d  ->  Wo row d*8 + h + 4*br
      int brn = kk >> 8, hh = (kk >> 6) & 3, dd = kk & 63;
      int srow = dd * 8 + hh + 4 * brn;
      *(float4*)&Bs[kr][cq] = *(const float4*)&Wo[(long long)srow * 256 + n0 + cq];
    }
    __syncthreads();
    #pragma unroll
    for (int kk = 0; kk < 32; ++kk) {
      float4 a4 = *(float4*)&As[kk][ty << 2];
      float4 b0 = *(float4*)&Bs[kk][tx << 3];
      float4 b1 = *(float4*)&Bs[kk][(tx << 3) + 4];
      float av[4] = {a4.x, a4.y, a4.z, a4.w};
      float bv[8] = {b0.x, b0.y, b0.z, b0.w, b1.x, b1.y, b1.z, b1.w};
      #pragma unroll
      for (int a = 0; a < 4; ++a)
        #pragma unroll
        for (int c = 0; c < 8; ++c) acc[a][c] += av[a] * bv[c];
    }
    __syncthreads();
  }
  #pragma unroll
  for (int a = 0; a < 4; ++a) {
    long long row = m0 + (ty << 2) + a;
    #pragma unroll
    for (int c = 0; c < 8; ++c) {
      int col = n0 + (tx << 3) + c;
      out[row * 256 + col] = acc[a][c] + bo[col];
    }
  }
}

extern "C" void kernel_launch(void* const* d_in, const int* in_sizes, int n_in,
                              void* d_out, int out_size, void* d_ws, size_t ws_size,
                              hipStream_t stream) {
  const float* e       = (const float*)d_in[0];
  const float* mask    = (const float*)d_in[1];
  const float* ln_g    = (const float*)d_in[2];
  const float* ln_b    = (const float*)d_in[3];
  const float* Wq_in   = (const float*)d_in[4];
  const float* bq_in   = (const float*)d_in[5];
  const float* Wkv_in  = (const float*)d_in[6];
  const float* bkv_in  = (const float*)d_in[7];
  const float* Weg_in  = (const float*)d_in[8];
  const float* beg_in  = (const float*)d_in[9];
  const float* Wq_out  = (const float*)d_in[10];
  const float* bq_out  = (const float*)d_in[11];
  const float* Wkv_out = (const float*)d_in[12];
  const float* bkv_out = (const float*)d_in[13];
  const float* Weg_out = (const float*)d_in[14];
  const float* beg_out = (const float*)d_in[15];
  const float* Wo      = (const float*)d_in[16];
  const float* bo      = (const float*)d_in[17];

  float* ws  = (float*)d_ws;
  float* eln = ws + OFF_ELN;
  float* Y   = ws + OFF_Y;
  float* Wp  = ws + OFF_WP;
  float* bp  = ws + OFF_BP;
  float* bin = ws + OFF_BIN;
  float* gin = ws + OFF_GIN;
  float* boT = ws + OFF_BOT;
  float* goT = ws + OFF_GOT;
  float* Va  = ws + OFF_VA;
  float* outp = (float*)d_out;

  hipLaunchKernelGGL(pack_kernel, dim3(((EDIM + 1) * PC + 255) / 256), dim3(256), 0, stream,
                     Wq_in, bq_in, Wkv_in, bkv_in, Weg_in, beg_in,
                     Wq_out, bq_out, Wkv_out, bkv_out, Weg_out, beg_out, Wp, bp);
  hipLaunchKernelGGL(ln_kernel, dim3(NNR / 4), dim3(256), 0, stream, e, ln_g, ln_b, eln);
  hipLaunchKernelGGL(proj_kernel, dim3(7, 400), dim3(256), 0, stream, eln, Wp, bp, Y);
  hipLaunchKernelGGL(eg_kernel, dim3(NNR * HH / 256), dim3(256), 0, stream, Y, mask, bin, gin, boT, goT);
  hipLaunchKernelGGL(attn_kernel, dim3(4, 160, 2), dim3(256), 0, stream, Y, bin, gin, boT, goT, Va);
  hipLaunchKernelGGL(out_kernel, dim3(2, 400), dim3(256), 0, stream, Va, Wo, bo, outp);
}

// Round 2
// 543.116 us; speedup vs baseline: 1.5110x; 1.5110x over previous
//
#include <hip/hip_runtime.h>

#define NTOK 160
#define EDIM 256
#define HH 4
#define DDIM 64
#define NNR 25600          // NTOK*NTOK rows
#define PC 784             // packed projection cols
#define YBC 768            // bf16 matmul cols
#define SCALEF 0.125f
#define LNEPS 1e-5f

// ---- workspace layout (float offsets) ----
#define OFF_ELN 0LL
#define OFF_YBF (OFF_ELN + (long long)NNR * EDIM)        // bf16: NNR x 768 (as half-floats)
#define OFF_YEG (OFF_YBF + (long long)NNR * YBC / 2)     // fp32: NNR x 16
#define OFF_WP  (OFF_YEG + (long long)NNR * 16)
#define OFF_BP  (OFF_WP  + (long long)EDIM * PC)
#define OFF_BIN (OFF_BP  + 1024LL)                       // each: HH*NNR floats, [h][r] planes
#define OFF_GIN (OFF_BIN + (long long)HH * NNR)
#define OFF_BOT (OFF_GIN + (long long)HH * NNR)
#define OFF_GOT (OFF_BOT + (long long)HH * NNR)
#define OFF_VA  (OFF_GOT + (long long)HH * NNR)
// end = OFF_VA + NNR*512 ≈ 30.5M floats (~122 MiB)

typedef short bf16x8 __attribute__((ext_vector_type(8)));
typedef unsigned short u16x8 __attribute__((ext_vector_type(8)));
typedef float f32x4 __attribute__((ext_vector_type(4)));

__device__ __forceinline__ unsigned short bf16_rne(float f) {
  unsigned int u = __float_as_uint(f);
  u += 0x7FFFu + ((u >> 16) & 1u);
  return (unsigned short)(u >> 16);
}

__device__ __forceinline__ float wave_sum(float v) {
  #pragma unroll
  for (int o = 1; o < 64; o <<= 1) v += __shfl_xor(v, o, 64);
  return v;
}
__device__ __forceinline__ float wave_max(float v) {
  #pragma unroll
  for (int o = 1; o < 64; o <<= 1) v = fmaxf(v, __shfl_xor(v, o, 64));
  return v;
}

// ---------------- pack weights: Wpack[256][784], bpack[784] ----------------
// col map: [0,256) Q_in (c=h*64+d <- Wq col d*4+h, *SCALE) | [256,320) K_in |
// [320,384) V_in | [384,388) E_in | [388,392) G_in | [392,648) Q_out |
// [648,712) K_out | [712,776) V_out | [776,780) E_out | [780,784) G_out
__global__ void pack_kernel(const float* __restrict__ Wq_in,  const float* __restrict__ bq_in,
                            const float* __restrict__ Wkv_in, const float* __restrict__ bkv_in,
                            const float* __restrict__ Weg_in, const float* __restrict__ beg_in,
                            const float* __restrict__ Wq_out, const float* __restrict__ bq_out,
                            const float* __restrict__ Wkv_out,const float* __restrict__ bkv_out,
                            const float* __restrict__ Weg_out,const float* __restrict__ beg_out,
                            float* __restrict__ Wp, float* __restrict__ bp) {
  int idx = blockIdx.x * blockDim.x + threadIdx.x;
  if (idx >= (EDIM + 1) * PC) return;
  int k = idx / PC, c = idx % PC;
  const float *W, *bias; int col, ncols; float scale = 1.f;
  if (c < 256)      { int h = c >> 6, d = c & 63; W = Wq_in;  bias = bq_in;  col = d*4+h; ncols = 256; scale = SCALEF; }
  else if (c < 320) { W = Wkv_in;  bias = bkv_in;  col = c - 256;        ncols = 128; }
  else if (c < 384) { W = Wkv_in;  bias = bkv_in;  col = 64 + (c - 320); ncols = 128; }
  else if (c < 388) { W = Weg_in;  bias = beg_in;  col = c - 384;        ncols = 8; }
  else if (c < 392) { W = Weg_in;  bias = beg_in;  col = 4 + (c - 388);  ncols = 8; }
  else if (c < 648) { int c2 = c - 392; int h = c2 >> 6, d = c2 & 63;
                      W = Wq_out;  bias = bq_out;  col = d*4+h; ncols = 256; scale = SCALEF; }
  else if (c < 712) { W = Wkv_out; bias = bkv_out; col = c - 648;        ncols = 128; }
  else if (c < 776) { W = Wkv_out; bias = bkv_out; col = 64 + (c - 712); ncols = 128; }
  else if (c < 780) { W = Weg_out; bias = beg_out; col = c - 776;        ncols = 8; }
  else              { W = Weg_out; bias = beg_out; col = 4 + (c - 780);  ncols = 8; }
  if (k < EDIM) Wp[(long long)k * PC + c] = W[(long long)k * ncols + col] * scale;
  else          bp[c] = bias[col] * scale;
}

// ---------------- layernorm: one wave per row ----------------
__global__ __launch_bounds__(256) void ln_kernel(const float* __restrict__ e,
                                                 const float* __restrict__ g,
                                                 const float* __restrict__ b,
                                                 float* __restrict__ eln) {
  int row  = blockIdx.x * 4 + (threadIdx.x >> 6);
  int lane = threadIdx.x & 63;
  float4 x = ((const float4*)(e + (long long)row * EDIM))[lane];
  float s = wave_sum(x.x + x.y + x.z + x.w);
  float mu = s * (1.f / EDIM);
  float d0 = x.x - mu, d1 = x.y - mu, d2 = x.z - mu, d3 = x.w - mu;
  float v = wave_sum(d0*d0 + d1*d1 + d2*d2 + d3*d3);
  float rs = rsqrtf(v * (1.f / EDIM) + LNEPS);
  float4 gg = ((const float4*)g)[lane], bb = ((const float4*)b)[lane];
  float4 y;
  y.x = d0 * rs * gg.x + bb.x;  y.y = d1 * rs * gg.y + bb.y;
  y.z = d2 * rs * gg.z + bb.z;  y.w = d3 * rs * gg.w + bb.w;
  ((float4*)(eln + (long long)row * EDIM))[lane] = y;
}

// ---------------- projection GEMM: (eln @ Wp + bp) -> Ybf (bf16) + Yeg (fp32 E/G) ----
__global__ __launch_bounds__(256) void proj_kernel(const float* __restrict__ A,
                                                   const float* __restrict__ Wp,
                                                   const float* __restrict__ bp,
                                                   unsigned short* __restrict__ Ybf,
                                                   float* __restrict__ Yeg) {
  __shared__ float As[32][68];    // [k][m]
  __shared__ float Bs[32][132];   // [k][n]
  const int n0 = blockIdx.x * 128;
  const int m0 = blockIdx.y * 64;
  const int t  = threadIdx.x;
  const int tx = t & 15, ty = t >> 4;
  float acc[4][8];
  #pragma unroll
  for (int a = 0; a < 4; ++a)
    #pragma unroll
    for (int c = 0; c < 8; ++c) acc[a][c] = 0.f;
  for (int k0 = 0; k0 < EDIM; k0 += 32) {
    #pragma unroll
    for (int p = 0; p < 2; ++p) {
      int f = t + p * 256;
      int r = f >> 3, kq = (f & 7) << 2;
      float4 a4 = *(const float4*)&A[(long long)(m0 + r) * EDIM + k0 + kq];
      As[kq + 0][r] = a4.x; As[kq + 1][r] = a4.y;
      As[kq + 2][r] = a4.z; As[kq + 3][r] = a4.w;
    }
    #pragma unroll
    for (int p = 0; p < 4; ++p) {
      int f = t + p * 256;
      int kr = f >> 5, cq = (f & 31) << 2;
      float4 b4 = make_float4(0.f, 0.f, 0.f, 0.f);
      if (n0 + cq + 4 <= PC)
        b4 = *(const float4*)&Wp[(long long)(k0 + kr) * PC + n0 + cq];
      *(float4*)&Bs[kr][cq] = b4;
    }
    __syncthreads();
    #pragma unroll
    for (int kk = 0; kk < 32; ++kk) {
      float4 a4 = *(float4*)&As[kk][ty << 2];
      float4 b0 = *(float4*)&Bs[kk][tx << 3];
      float4 b1 = *(float4*)&Bs[kk][(tx << 3) + 4];
      float av[4] = {a4.x, a4.y, a4.z, a4.w};
      float bv[8] = {b0.x, b0.y, b0.z, b0.w, b1.x, b1.y, b1.z, b1.w};
      #pragma unroll
      for (int a = 0; a < 4; ++a)
        #pragma unroll
        for (int c = 0; c < 8; ++c) acc[a][c] += av[a] * bv[c];
    }
    __syncthreads();
  }
  const int col0 = n0 + (tx << 3);   // multiple of 8; chunks never straddle segment bounds
  #pragma unroll
  for (int a = 0; a < 4; ++a) {
    long long row = m0 + (ty << 2) + a;
    if (col0 >= PC) continue;
    float vals[8];
    #pragma unroll
    for (int c = 0; c < 8; ++c) vals[c] = acc[a][c] + bp[col0 + c];
    if (col0 == 384 || col0 == 776) {
      int base = (col0 == 384) ? 0 : 8;
      #pragma unroll
      for (int c = 0; c < 8; ++c) Yeg[row * 16 + base + c] = vals[c];
    } else {
      int yc = col0 - (col0 >= 392 ? 8 : 0);
      u16x8 pk;
      #pragma unroll
      for (int c = 0; c < 8; ++c) pk[c] = bf16_rne(vals[c]);
      *(u16x8*)&Ybf[row * YBC + yc] = pk;
    }
  }
}

// ---------------- E/G precompute: planes [h][NNR]; out-branch transposed ----------------
__global__ void eg_kernel(const float* __restrict__ Yeg, const float* __restrict__ mask,
                          float* __restrict__ binP, float* __restrict__ ginP,
                          float* __restrict__ boTP, float* __restrict__ goTP) {
  int r = blockIdx.x * blockDim.x + threadIdx.x;
  if (r >= NNR) return;
  float m = mask[r];
  const float* yr = Yeg + (long long)r * 16;
  int i = r % NTOK, k = r / NTOK;
  int rt = i * NTOK + k;
  #pragma unroll
  for (int h = 0; h < HH; ++h) {
    binP[h * NNR + r]  = yr[h] + m;
    ginP[h * NNR + r]  = 1.f / (1.f + __expf(-(yr[4 + h] + m)));
    boTP[h * NNR + rt] = yr[8 + h] + m;
    goTP[h * NNR + rt] = 1.f / (1.f + __expf(-(yr[12 + h] + m)));
  }
}

// ---------------- MFMA attention: grid (10 i-tiles, 160 j, 2 branch), 256 thr ----------------
// Ybf cols: 0 Qin(h-major,256) | 256 Kin(64) | 320 Vin(64) | 384 Qout(256) | 640 Kout | 704 Vout
__global__ __launch_bounds__(256) void attn_kernel(const unsigned short* __restrict__ Ybf,
                                                   const float* __restrict__ binP,
                                                   const float* __restrict__ ginP,
                                                   const float* __restrict__ boTP,
                                                   const float* __restrict__ goTP,
                                                   float* __restrict__ Va) {
  __shared__ unsigned short Kl[192][72];   // [k_token][d], +8 pad (2-way banks), rows 160..192 zero
  __shared__ unsigned short Vt[64][200];   // [d][k_token], cols 160..200 zero
  __shared__ unsigned short Ql[HH][16][72];
  __shared__ float          Sl[16][196];   // scores fp32
  __shared__ unsigned short Pl[16][200];   // probs bf16 (A-layout rows)
  const int i0 = blockIdx.x * 16;
  const int j  = blockIdx.y;
  const int br = blockIdx.z;
  const int t  = threadIdx.x;
  const int kb = br ? 640 : 256, vb = kb + 64, qb = br ? 384 : 0;
  const float* bias = br ? boTP : binP;
  const float* gate = br ? goTP : ginP;

  // ---- stage K [160][64] (+zero pad rows) ----
  for (int f = t; f < 160 * 8; f += 256) {
    int k = f >> 3, c = (f & 7) << 3;
    long long row = br ? ((long long)k * NTOK + j) : ((long long)j * NTOK + k);
    *(u16x8*)&Kl[k][c] = *(const u16x8*)&Ybf[row * YBC + kb + c];
  }
  for (int f = t; f < 32 * 72; f += 256) Kl[160 + f / 72][f % 72] = 0;
  // ---- stage V transposed [d][k] (rotated write order -> 2-way banks) ----
  for (int f = t; f < 160 * 8; f += 256) {
    int k = f >> 3, g = f & 7, c = g << 3;
    long long row = br ? ((long long)k * NTOK + j) : ((long long)j * NTOK + k);
    u16x8 v = *(const u16x8*)&Ybf[row * YBC + vb + c];
    #pragma unroll
    for (int m = 0; m < 8; ++m) { int mm = (m + g) & 7; Vt[c + mm][k] = v[mm]; }
  }
  for (int f = t; f < 64 * 40; f += 256) Vt[f / 40][160 + f % 40] = 0;
  // ---- stage Q, all heads [4][16][64] ----
  for (int f = t; f < 16 * 32; f += 256) {
    int m = f >> 5, c = (f & 31) << 3;
    u16x8 q = *(const u16x8*)&Ybf[(long long)((i0 + m) * NTOK + j) * YBC + qb + c];
    *(u16x8*)&Ql[c >> 6][m][c & 63] = q;
  }
  __syncthreads();

  const int lane = t & 63, w = t >> 6;
  const int quad = lane >> 4, l15 = lane & 15;

  for (int h = 0; h < HH; ++h) {
    // ---- QK^T: wave w owns N-tiles 3w..3w+2 (k_token), M-tile 0 ----
    f32x4 acc0 = {0.f,0.f,0.f,0.f}, acc1 = acc0, acc2 = acc0;
    #pragma unroll
    for (int ks = 0; ks < 2; ++ks) {
      bf16x8 af = *(const bf16x8*)&Ql[h][l15][ks * 32 + quad * 8];
      bf16x8 b0 = *(const bf16x8*)&Kl[(3 * w + 0) * 16 + l15][ks * 32 + quad * 8];
      bf16x8 b1 = *(const bf16x8*)&Kl[(3 * w + 1) * 16 + l15][ks * 32 + quad * 8];
      bf16x8 b2 = *(const bf16x8*)&Kl[(3 * w + 2) * 16 + l15][ks * 32 + quad * 8];
      acc0 = __builtin_amdgcn_mfma_f32_16x16x32_bf16(af, b0, acc0, 0, 0, 0);
      acc1 = __builtin_amdgcn_mfma_f32_16x16x32_bf16(af, b1, acc1, 0, 0, 0);
      acc2 = __builtin_amdgcn_mfma_f32_16x16x32_bf16(af, b2, acc2, 0, 0, 0);
    }
    #pragma unroll
    for (int r = 0; r < 4; ++r) {
      int i = quad * 4 + r;
      Sl[i][(3 * w + 0) * 16 + l15] = acc0[r];
      Sl[i][(3 * w + 1) * 16 + l15] = acc1[r];
      Sl[i][(3 * w + 2) * 16 + l15] = acc2[r];
    }
    __syncthreads();
    // ---- softmax+gate: wave w rows {w, w+4, w+8, w+12} ----
    #pragma unroll
    for (int rr = 0; rr < 4; ++rr) {
      int i = w + rr * 4;
      long long bb = (long long)h * NNR + (long long)(i0 + i) * NTOK;
      float l0 = Sl[i][lane]       + bias[bb + lane];
      float l1 = Sl[i][lane + 64]  + bias[bb + lane + 64];
      float l2 = (lane < 32) ? Sl[i][lane + 128] + bias[bb + lane + 128] : -3.0e38f;
      float mx = wave_max(fmaxf(fmaxf(l0, l1), l2));
      float p0 = __expf(l0 - mx), p1 = __expf(l1 - mx);
      float p2 = (lane < 32) ? __expf(l2 - mx) : 0.f;
      float inv = 1.f / wave_sum(p0 + p1 + p2);
      Pl[i][lane]       = bf16_rne(p0 * inv * gate[bb + lane]);
      Pl[i][lane + 64]  = bf16_rne(p1 * inv * gate[bb + lane + 64]);
      Pl[i][lane + 128] = (lane < 32) ? bf16_rne(p2 * inv * gate[bb + lane + 128])
                                      : (unsigned short)0;   // zero pad k=160..191
    }
    __syncthreads();
    // ---- PV: wave w owns d-tile w ----
    f32x4 o = {0.f,0.f,0.f,0.f};
    #pragma unroll
    for (int ks = 0; ks < 6; ++ks) {
      bf16x8 af = *(const bf16x8*)&Pl[l15][ks * 32 + quad * 8];
      bf16x8 bf = *(const bf16x8*)&Vt[w * 16 + l15][ks * 32 + quad * 8];
      o = __builtin_amdgcn_mfma_f32_16x16x32_bf16(af, bf, o, 0, 0, 0);
    }
    #pragma unroll
    for (int r = 0; r < 4; ++r) {
      int i = quad * 4 + r;
      Va[(long long)((i0 + i) * NTOK + j) * 512 + br * 256 + h * 64 + w * 16 + l15] = o[r];
    }
    __syncthreads();
  }
}

// ---------------- output GEMM: out = Va2 @ Wo(perm rows) + bo ----------------
__global__ __launch_bounds__(256) void out_kernel(const float* __restrict__ Va,
                                                  const float* __restrict__ Wo,
                                                  const float* __restrict__ bo,
                                                  float* __restrict__ out) {
  __shared__ float As[32][68];
  __shared__ float Bs[32][132];
  const int n0 = blockIdx.x * 128;
  const int m0 = blockIdx.y * 64;
  const int t  = threadIdx.x;
  const int tx = t & 15, ty = t >> 4;
  float acc[4][8];
  #pragma unroll
  for (int a = 0; a < 4; ++a)
    #pragma unroll
    for (int c = 0; c < 8; ++c) acc[a][c] = 0.f;
  for (int k0 = 0; k0 < 512; k0 += 32) {
    #pragma unroll
    for (int p = 0; p < 2; ++p) {
      int f = t + p * 256;
      int r = f >> 3, kq = (f & 7) << 2;
      float4 a4 = *(const float4*)&Va[(long long)(m0 + r) * 512 + k0 + kq];
      As[kq + 0][r] = a4.x; As[kq + 1][r] = a4.y;
      As[kq + 2][r] = a4.z; As[kq + 3][r] = a4.w;
    }
    #pragma unroll
    for (int p = 0; p < 4; ++p) {
      int f = t + p * 256;
      int kr = f >> 5, cq = (f & 31) << 2;
      int kk = k0 + kr;
      int brn = kk >> 8, hh = (kk >> 6) & 3, dd = kk & 63;
      int srow = dd * 8 + hh + 4 * brn;
      *(float4*)&Bs[kr][cq] = *(const float4*)&Wo[(long long)srow * 256 + n0 + cq];
    }
    __syncthreads();
    #pragma unroll
    for (int kk = 0; kk < 32; ++kk) {
      float4 a4 = *(float4*)&As[kk][ty << 2];
      float4 b0 = *(float4*)&Bs[kk][tx << 3];
      float4 b1 = *(float4*)&Bs[kk][(tx << 3) + 4];
      float av[4] = {a4.x, a4.y, a4.z, a4.w};
      float bv[8] = {b0.x, b0.y, b0.z, b0.w, b1.x, b1.y, b1.z, b1.w};
      #pragma unroll
      for (int a = 0; a < 4; ++a)
        #pragma unroll
        for (int c = 0; c < 8; ++c) acc[a][c] += av[a] * bv[c];
    }
    __syncthreads();
  }
  #pragma unroll
  for (int a = 0; a < 4; ++a) {
    long long row = m0 + (ty << 2) + a;
    #pragma unroll
    for (int c = 0; c < 8; ++c) {
      int col = n0 + (tx << 3) + c;
      out[row * 256 + col] = acc[a][c] + bo[col];
    }
  }
}

extern "C" void kernel_launch(void* const* d_in, const int* in_sizes, int n_in,
                              void* d_out, int out_size, void* d_ws, size_t ws_size,
                              hipStream_t stream) {
  const float* e       = (const float*)d_in[0];
  const float* mask    = (const float*)d_in[1];
  const float* ln_g    = (const float*)d_in[2];
  const float* ln_b    = (const float*)d_in[3];
  const float* Wq_in   = (const float*)d_in[4];
  const float* bq_in   = (const float*)d_in[5];
  const float* Wkv_in  = (const float*)d_in[6];
  const float* bkv_in  = (const float*)d_in[7];
  const float* Weg_in  = (const float*)d_in[8];
  const float* beg_in  = (const float*)d_in[9];
  const float* Wq_out  = (const float*)d_in[10];
  const float* bq_out  = (const float*)d_in[11];
  const float* Wkv_out = (const float*)d_in[12];
  const float* bkv_out = (const float*)d_in[13];
  const float* Weg_out = (const float*)d_in[14];
  const float* beg_out = (const float*)d_in[15];
  const float* Wo      = (const float*)d_in[16];
  const float* bo      = (const float*)d_in[17];

  float* ws   = (float*)d_ws;
  float* eln  = ws + OFF_ELN;
  unsigned short* Ybf = (unsigned short*)(ws + OFF_YBF);
  float* Yeg  = ws + OFF_YEG;
  float* Wp   = ws + OFF_WP;
  float* bp   = ws + OFF_BP;
  float* binP = ws + OFF_BIN;
  float* ginP = ws + OFF_GIN;
  float* boTP = ws + OFF_BOT;
  float* goTP = ws + OFF_GOT;
  float* Vaf  = ws + OFF_VA;
  float* outp = (float*)d_out;

  hipLaunchKernelGGL(pack_kernel, dim3(((EDIM + 1) * PC + 255) / 256), dim3(256), 0, stream,
                     Wq_in, bq_in, Wkv_in, bkv_in, Weg_in, beg_in,
                     Wq_out, bq_out, Wkv_out, bkv_out, Weg_out, beg_out, Wp, bp);
  hipLaunchKernelGGL(ln_kernel, dim3(NNR / 4), dim3(256), 0, stream, e, ln_g, ln_b, eln);
  hipLaunchKernelGGL(proj_kernel, dim3(7, 400), dim3(256), 0, stream, eln, Wp, bp, Ybf, Yeg);
  hipLaunchKernelGGL(eg_kernel, dim3((NNR + 255) / 256), dim3(256), 0, stream, Yeg, mask, binP, ginP, boTP, goTP);
  hipLaunchKernelGGL(attn_kernel, dim3(10, 160, 2), dim3(256), 0, stream, Ybf, binP, ginP, boTP, goTP, Vaf);
  hipLaunchKernelGGL(out_kernel, dim3(2, 400), dim3(256), 0, stream, Vaf, Wo, bo, outp);
}

// Round 3
// 237.008 us; speedup vs baseline: 3.4625x; 2.2915x over previous
//
#include <hip/hip_runtime.h>

#define NTOK 160
#define EDIM 256
#define HH 4
#define NNR 25600          // NTOK*NTOK rows
#define PC 784             // packed projection cols
#define YBC 768            // bf16 matmul cols of Y
#define SCALEF 0.125f
#define LNEPS 1e-5f

// ---- workspace layout (float offsets) ----
#define OFF_ELN 0LL                      // bf16 [NNR][256]
#define OFF_YBF (OFF_ELN + 3276800LL)    // bf16 [NNR][768]
#define OFF_YEG (OFF_YBF + 9830400LL)    // fp32 [NNR][16]
#define OFF_WPT (OFF_YEG + 409600LL)     // bf16 [784][256]
#define OFF_BP  (OFF_WPT + 100352LL)     // fp32 [784]
#define OFF_WOT (OFF_BP  + 800LL)        // bf16 [256][512]
#define OFF_BGI (OFF_WOT + 65536LL)      // float2 [4][NNR]
#define OFF_BGO (OFF_BGI + 204800LL)     // float2 [4][NNR]
#define OFF_VAB (OFF_BGO + 204800LL)     // bf16 [NNR][512]
// end = OFF_VAB + 6,553,600 = 20,646,688 floats (~83 MiB)

typedef short bf16x8 __attribute__((ext_vector_type(8)));
typedef unsigned short u16x8 __attribute__((ext_vector_type(8)));
typedef unsigned short u16x4 __attribute__((ext_vector_type(4)));
typedef float f32x4 __attribute__((ext_vector_type(4)));

__device__ __forceinline__ unsigned short bf16_rne(float f) {
  unsigned int u = __float_as_uint(f);
  u += 0x7FFFu + ((u >> 16) & 1u);
  return (unsigned short)(u >> 16);
}

__device__ __forceinline__ float wave_sum(float v) {
  #pragma unroll
  for (int o = 1; o < 64; o <<= 1) v += __shfl_xor(v, o, 64);
  return v;
}

// ---------------- pack: WpT[784][256] bf16, bp[784] f32, WoT[256][512] bf16 ----
// packed col map n: [0,256) Qin(h-major, *SCALE) | [256,320) Kin | [320,384) Vin |
// [384,640) Qout | [640,704) Kout | [704,768) Vout |
// [768,772) E_in | [772,776) G_in | [776,780) E_out | [780,784) G_out
__device__ __forceinline__ void col_map(int n, const float* const* W, const float* const* bia,
                                        const float** Wsel, const float** bsel,
                                        int* col, int* ld, float* scale) {
  *scale = 1.f;
  if (n < 256)      { *Wsel = W[0]; *bsel = bia[0]; *col = (n&63)*4 + (n>>6); *ld = 256; *scale = SCALEF; }
  else if (n < 320) { *Wsel = W[1]; *bsel = bia[1]; *col = n - 256;        *ld = 128; }
  else if (n < 384) { *Wsel = W[1]; *bsel = bia[1]; *col = 64 + n - 320;   *ld = 128; }
  else if (n < 640) { int c2 = n - 384; *Wsel = W[3]; *bsel = bia[3]; *col = (c2&63)*4 + (c2>>6); *ld = 256; *scale = SCALEF; }
  else if (n < 704) { *Wsel = W[4]; *bsel = bia[4]; *col = n - 640;        *ld = 128; }
  else if (n < 768) { *Wsel = W[4]; *bsel = bia[4]; *col = 64 + n - 704;   *ld = 128; }
  else if (n < 772) { *Wsel = W[2]; *bsel = bia[2]; *col = n - 768;        *ld = 8; }
  else if (n < 776) { *Wsel = W[2]; *bsel = bia[2]; *col = 4 + n - 772;    *ld = 8; }
  else if (n < 780) { *Wsel = W[5]; *bsel = bia[5]; *col = n - 776;        *ld = 8; }
  else              { *Wsel = W[5]; *bsel = bia[5]; *col = 4 + n - 780;    *ld = 8; }
}

__global__ void pack_kernel(const float* __restrict__ Wq_in,  const float* __restrict__ bq_in,
                            const float* __restrict__ Wkv_in, const float* __restrict__ bkv_in,
                            const float* __restrict__ Weg_in, const float* __restrict__ beg_in,
                            const float* __restrict__ Wq_out, const float* __restrict__ bq_out,
                            const float* __restrict__ Wkv_out,const float* __restrict__ bkv_out,
                            const float* __restrict__ Weg_out,const float* __restrict__ beg_out,
                            const float* __restrict__ Wo,
                            unsigned short* __restrict__ WpT, float* __restrict__ bp,
                            unsigned short* __restrict__ WoT) {
  const float* W[6]  = {Wq_in, Wkv_in, Weg_in, Wq_out, Wkv_out, Weg_out};
  const float* bi[6] = {bq_in, bkv_in, beg_in, bq_out, bkv_out, beg_out};
  int idx = blockIdx.x * blockDim.x + threadIdx.x;
  if (idx < PC * 256) {
    int n = idx >> 8, k = idx & 255;
    const float *Ws, *bs; int col, ld; float sc;
    col_map(n, W, bi, &Ws, &bs, &col, &ld, &sc);
    WpT[idx] = bf16_rne(Ws[(long long)k * ld + col] * sc);
  } else if (idx < PC * 256 + PC) {
    int n = idx - PC * 256;
    const float *Ws, *bs; int col, ld; float sc;
    col_map(n, W, bi, &Ws, &bs, &col, &ld, &sc);
    bp[n] = bs[col] * sc;
  } else if (idx < PC * 256 + PC + 256 * 512) {
    int q = idx - (PC * 256 + PC);
    int n = q >> 9, kk = q & 511;
    int brn = kk >> 8, hh = (kk >> 6) & 3, dd = kk & 63;
    WoT[q] = bf16_rne(Wo[(long long)(dd * 8 + hh + 4 * brn) * 256 + n]);
  }
}

// ---------------- layernorm -> bf16: one wave per row ----------------
__global__ __launch_bounds__(256) void ln_kernel(const float* __restrict__ e,
                                                 const float* __restrict__ g,
                                                 const float* __restrict__ b,
                                                 unsigned short* __restrict__ elnbf) {
  int row  = blockIdx.x * 4 + (threadIdx.x >> 6);
  int lane = threadIdx.x & 63;
  float4 x = ((const float4*)(e + (long long)row * EDIM))[lane];
  float s = wave_sum(x.x + x.y + x.z + x.w);
  float mu = s * (1.f / EDIM);
  float d0 = x.x - mu, d1 = x.y - mu, d2 = x.z - mu, d3 = x.w - mu;
  float v = wave_sum(d0*d0 + d1*d1 + d2*d2 + d3*d3);
  float rs = rsqrtf(v * (1.f / EDIM) + LNEPS);
  float4 gg = ((const float4*)g)[lane], bb = ((const float4*)b)[lane];
  u16x4 y;
  y[0] = bf16_rne(d0 * rs * gg.x + bb.x);
  y[1] = bf16_rne(d1 * rs * gg.y + bb.y);
  y[2] = bf16_rne(d2 * rs * gg.z + bb.z);
  y[3] = bf16_rne(d3 * rs * gg.w + bb.w);
  *(u16x4*)&elnbf[(long long)row * EDIM + lane * 4] = y;
}

// ---------------- projection GEMM (MFMA): Y = eln @ Wp + bp ----------------
// grid (7 nblk x 112, 200 mblk x 128), 256 thr, wave w owns rows w*32..+31
__global__ __launch_bounds__(256) void proj_kernel(const unsigned short* __restrict__ Abf,
                                                   const unsigned short* __restrict__ WpT,
                                                   const float* __restrict__ bp,
                                                   unsigned short* __restrict__ Ybf,
                                                   float* __restrict__ Yeg) {
  __shared__ unsigned short As[128][40];
  __shared__ unsigned short Bs[112][40];
  const int n0 = blockIdx.x * 112;
  const int m0 = blockIdx.y * 128;
  const int t = threadIdx.x;
  const int lane = t & 63, w = t >> 6;
  const int quad = lane >> 4, l15 = lane & 15;
  f32x4 acc[2][7];
  #pragma unroll
  for (int a = 0; a < 2; ++a)
    #pragma unroll
    for (int c = 0; c < 7; ++c) acc[a][c] = (f32x4){0.f,0.f,0.f,0.f};
  for (int k0 = 0; k0 < 256; k0 += 32) {
    #pragma unroll
    for (int p = 0; p < 2; ++p) {
      int f = t + p * 256;
      int row = f >> 2, cq = (f & 3) << 3;
      *(u16x8*)&As[row][cq] = *(const u16x8*)&Abf[(long long)(m0 + row) * 256 + k0 + cq];
    }
    #pragma unroll
    for (int p = 0; p < 2; ++p) {
      int f = t + p * 256;
      int row = f >> 2, cq = (f & 3) << 3;
      if (row < 112)
        *(u16x8*)&Bs[row][cq] = *(const u16x8*)&WpT[(long long)(n0 + row) * 256 + k0 + cq];
    }
    __syncthreads();
    bf16x8 a0 = *(const bf16x8*)&As[w * 32 + l15][quad * 8];
    bf16x8 a1 = *(const bf16x8*)&As[w * 32 + 16 + l15][quad * 8];
    #pragma unroll
    for (int nt = 0; nt < 7; ++nt) {
      bf16x8 bfr = *(const bf16x8*)&Bs[nt * 16 + l15][quad * 8];
      acc[0][nt] = __builtin_amdgcn_mfma_f32_16x16x32_bf16(a0, bfr, acc[0][nt], 0, 0, 0);
      acc[1][nt] = __builtin_amdgcn_mfma_f32_16x16x32_bf16(a1, bfr, acc[1][nt], 0, 0, 0);
    }
    __syncthreads();
  }
  #pragma unroll
  for (int nt = 0; nt < 7; ++nt) {
    int col = n0 + nt * 16 + l15;
    float bias = bp[col];
    #pragma unroll
    for (int mt = 0; mt < 2; ++mt) {
      #pragma unroll
      for (int r = 0; r < 4; ++r) {
        long long row = m0 + w * 32 + mt * 16 + quad * 4 + r;
        float v = acc[mt][nt][r] + bias;
        if (col < YBC) Ybf[row * YBC + col] = bf16_rne(v);
        else           Yeg[row * 16 + (col - YBC)] = v;
      }
    }
  }
}

// ---------------- E/G precompute: float2 (bias, gate) planes [h][NNR] ----------------
__global__ void eg_kernel(const float* __restrict__ Yeg, const float* __restrict__ mask,
                          float2* __restrict__ bgIn, float2* __restrict__ bgOut) {
  int r = blockIdx.x * blockDim.x + threadIdx.x;
  if (r >= NNR) return;
  float m = mask[r];
  const float* yr = Yeg + (long long)r * 16;
  int i = r % NTOK, k = r / NTOK;
  long long rt = (long long)i * NTOK + k;
  #pragma unroll
  for (int h = 0; h < HH; ++h) {
    bgIn [h * NNR + r]  = make_float2(yr[h] + m,     1.f / (1.f + __expf(-(yr[4 + h] + m))));
    bgOut[h * NNR + rt] = make_float2(yr[8 + h] + m, 1.f / (1.f + __expf(-(yr[12 + h] + m))));
  }
}

// ---------------- attention: wave = head, one barrier. grid (10, 160, 2) ----------------
__global__ __launch_bounds__(256) void attn_kernel(const unsigned short* __restrict__ Ybf,
                                                   const float2* __restrict__ bgIn,
                                                   const float2* __restrict__ bgOut,
                                                   unsigned short* __restrict__ Vab) {
  __shared__ unsigned short Kl[160][72];       // [k_token][d]
  __shared__ unsigned short Vt[64][168];       // [d][k_token]
  __shared__ unsigned short Pl[HH][16][168];   // per-head probs (A-layout rows)
  const int i0 = blockIdx.x * 16;
  const int j  = blockIdx.y;
  const int br = blockIdx.z;
  const int t  = threadIdx.x;
  const int kb = br ? 640 : 256, vb = kb + 64, qb = br ? 384 : 0;
  const float2* bg = br ? bgOut : bgIn;

  for (int f = t; f < 160 * 8; f += 256) {
    int k = f >> 3, c = (f & 7) << 3;
    long long row = br ? ((long long)k * NTOK + j) : ((long long)j * NTOK + k);
    *(u16x8*)&Kl[k][c] = *(const u16x8*)&Ybf[row * YBC + kb + c];
  }
  for (int f = t; f < 160 * 8; f += 256) {
    int k = f >> 3, g = f & 7, c = g << 3;
    long long row = br ? ((long long)k * NTOK + j) : ((long long)j * NTOK + k);
    u16x8 v = *(const u16x8*)&Ybf[row * YBC + vb + c];
    #pragma unroll
    for (int m = 0; m < 8; ++m) { int mm = (m + g) & 7; Vt[c + mm][k] = v[mm]; }
  }
  __syncthreads();

  const int lane = t & 63, h = t >> 6;     // wave w == head h
  const int quad = lane >> 4, l15 = lane & 15;

  // ---- QK^T: S[i=quad*4+r][kt=n*16+l15] in registers ----
  f32x4 acc[10];
  #pragma unroll
  for (int n = 0; n < 10; ++n) acc[n] = (f32x4){0.f,0.f,0.f,0.f};
  const unsigned short* qp = &Ybf[((long long)(i0 + l15) * NTOK + j) * YBC + qb + h * 64 + quad * 8];
  bf16x8 a0 = *(const bf16x8*)qp;
  bf16x8 a1 = *(const bf16x8*)(qp + 32);
  #pragma unroll
  for (int n = 0; n < 10; ++n) {
    acc[n] = __builtin_amdgcn_mfma_f32_16x16x32_bf16(a0, *(const bf16x8*)&Kl[n*16 + l15][quad*8],      acc[n], 0,0,0);
    acc[n] = __builtin_amdgcn_mfma_f32_16x16x32_bf16(a1, *(const bf16x8*)&Kl[n*16 + l15][32 + quad*8], acc[n], 0,0,0);
  }
  // ---- softmax (sum-only: logits are O(1); normalization deferred to PV output) ----
  float sum[4] = {0.f, 0.f, 0.f, 0.f};
  const float2* bgh = bg + (long long)h * NNR + (long long)i0 * NTOK;
  #pragma unroll
  for (int n = 0; n < 10; ++n) {
    #pragma unroll
    for (int r = 0; r < 4; ++r) {
      float2 b2 = bgh[(quad * 4 + r) * NTOK + n * 16 + l15];
      float q = __expf(acc[n][r] + b2.x);
      sum[r] += q;
      Pl[h][quad * 4 + r][n * 16 + l15] = bf16_rne(q * b2.y);
    }
  }
  #pragma unroll
  for (int r = 0; r < 4; ++r) {
    #pragma unroll
    for (int m = 1; m < 16; m <<= 1) sum[r] += __shfl_xor(sum[r], m, 64);
  }
  // ---- PV: o[dt][r], rows match QK rows -> in-lane normalization ----
  f32x4 o[4];
  #pragma unroll
  for (int d = 0; d < 4; ++d) o[d] = (f32x4){0.f,0.f,0.f,0.f};
  #pragma unroll
  for (int ks = 0; ks < 5; ++ks) {
    bf16x8 af = *(const bf16x8*)&Pl[h][l15][ks * 32 + quad * 8];
    #pragma unroll
    for (int d = 0; d < 4; ++d)
      o[d] = __builtin_amdgcn_mfma_f32_16x16x32_bf16(af, *(const bf16x8*)&Vt[d*16 + l15][ks*32 + quad*8], o[d], 0,0,0);
  }
  float inv[4];
  #pragma unroll
  for (int r = 0; r < 4; ++r) inv[r] = 1.f / sum[r];
  #pragma unroll
  for (int d = 0; d < 4; ++d)
    #pragma unroll
    for (int r = 0; r < 4; ++r)
      Vab[((long long)(i0 + quad*4 + r) * NTOK + j) * 512 + br*256 + h*64 + d*16 + l15] =
          bf16_rne(o[d][r] * inv[r]);
}

// ---------------- output GEMM (MFMA): out = Va @ WoT^T + bo ----------------
__global__ __launch_bounds__(256) void out_kernel(const unsigned short* __restrict__ Vab,
                                                  const unsigned short* __restrict__ WoT,
                                                  const float* __restrict__ bo,
                                                  float* __restrict__ out) {
  __shared__ unsigned short As[128][40];
  __shared__ unsigned short Bs[128][40];
  const int n0 = blockIdx.x * 128;
  const int m0 = blockIdx.y * 128;
  const int t = threadIdx.x;
  const int lane = t & 63, w = t >> 6;
  const int quad = lane >> 4, l15 = lane & 15;
  f32x4 acc[2][8];
  #pragma unroll
  for (int a = 0; a < 2; ++a)
    #pragma unroll
    for (int c = 0; c < 8; ++c) acc[a][c] = (f32x4){0.f,0.f,0.f,0.f};
  for (int k0 = 0; k0 < 512; k0 += 32) {
    #pragma unroll
    for (int p = 0; p < 2; ++p) {
      int f = t + p * 256;
      int row = f >> 2, cq = (f & 3) << 3;
      *(u16x8*)&As[row][cq] = *(const u16x8*)&Vab[(long long)(m0 + row) * 512 + k0 + cq];
      *(u16x8*)&Bs[row][cq] = *(const u16x8*)&WoT[(long long)(n0 + row) * 512 + k0 + cq];
    }
    __syncthreads();
    bf16x8 a0 = *(const bf16x8*)&As[w * 32 + l15][quad * 8];
    bf16x8 a1 = *(const bf16x8*)&As[w * 32 + 16 + l15][quad * 8];
    #pragma unroll
    for (int nt = 0; nt < 8; ++nt) {
      bf16x8 bfr = *(const bf16x8*)&Bs[nt * 16 + l15][quad * 8];
      acc[0][nt] = __builtin_amdgcn_mfma_f32_16x16x32_bf16(a0, bfr, acc[0][nt], 0, 0, 0);
      acc[1][nt] = __builtin_amdgcn_mfma_f32_16x16x32_bf16(a1, bfr, acc[1][nt], 0, 0, 0);
    }
    __syncthreads();
  }
  #pragma unroll
  for (int nt = 0; nt < 8; ++nt) {
    int col = n0 + nt * 16 + l15;
    float bias = bo[col];
    #pragma unroll
    for (int mt = 0; mt < 2; ++mt) {
      #pragma unroll
      for (int r = 0; r < 4; ++r) {
        long long row = m0 + w * 32 + mt * 16 + quad * 4 + r;
        out[row * 256 + col] = acc[mt][nt][r] + bias;
      }
    }
  }
}

extern "C" void kernel_launch(void* const* d_in, const int* in_sizes, int n_in,
                              void* d_out, int out_size, void* d_ws, size_t ws_size,
                              hipStream_t stream) {
  const float* e       = (const float*)d_in[0];
  const float* mask    = (const float*)d_in[1];
  const float* ln_g    = (const float*)d_in[2];
  const float* ln_b    = (const float*)d_in[3];
  const float* Wq_in   = (const float*)d_in[4];
  const float* bq_in   = (const float*)d_in[5];
  const float* Wkv_in  = (const float*)d_in[6];
  const float* bkv_in  = (const float*)d_in[7];
  const float* Weg_in  = (const float*)d_in[8];
  const float* beg_in  = (const float*)d_in[9];
  const float* Wq_out  = (const float*)d_in[10];
  const float* bq_out  = (const float*)d_in[11];
  const float* Wkv_out = (const float*)d_in[12];
  const float* bkv_out = (const float*)d_in[13];
  const float* Weg_out = (const float*)d_in[14];
  const float* beg_out = (const float*)d_in[15];
  const float* Wo      = (const float*)d_in[16];
  const float* bo      = (const float*)d_in[17];

  float* ws = (float*)d_ws;
  unsigned short* elnbf = (unsigned short*)(ws + OFF_ELN);
  unsigned short* Ybf   = (unsigned short*)(ws + OFF_YBF);
  float* Yeg            = ws + OFF_YEG;
  unsigned short* WpT   = (unsigned short*)(ws + OFF_WPT);
  float* bp             = ws + OFF_BP;
  unsigned short* WoT   = (unsigned short*)(ws + OFF_WOT);
  float2* bgIn          = (float2*)(ws + OFF_BGI);
  float2* bgOut         = (float2*)(ws + OFF_BGO);
  unsigned short* Vab   = (unsigned short*)(ws + OFF_VAB);
  float* outp = (float*)d_out;

  int pack_total = PC * 256 + PC + 256 * 512;
  hipLaunchKernelGGL(pack_kernel, dim3((pack_total + 255) / 256), dim3(256), 0, stream,
                     Wq_in, bq_in, Wkv_in, bkv_in, Weg_in, beg_in,
                     Wq_out, bq_out, Wkv_out, bkv_out, Weg_out, beg_out, Wo,
                     WpT, bp, WoT);
  hipLaunchKernelGGL(ln_kernel, dim3(NNR / 4), dim3(256), 0, stream, e, ln_g, ln_b, elnbf);
  hipLaunchKernelGGL(proj_kernel, dim3(7, 200), dim3(256), 0, stream, elnbf, WpT, bp, Ybf, Yeg);
  hipLaunchKernelGGL(eg_kernel, dim3((NNR + 255) / 256), dim3(256), 0, stream, Yeg, mask, bgIn, bgOut);
  hipLaunchKernelGGL(attn_kernel, dim3(10, 160, 2), dim3(256), 0, stream, Ybf, bgIn, bgOut, Vab);
  hipLaunchKernelGGL(out_kernel, dim3(2, 200), dim3(256), 0, stream, Vab, WoT, bo, outp);
}